// Round 6
// baseline (62.211 us; speedup 1.0000x reference)
//
#include <hip/hip_runtime.h>

typedef __bf16 bf16x8 __attribute__((ext_vector_type(8)));
typedef float f32x4 __attribute__((ext_vector_type(4)));

#define S_LEN 2048
#define D_DIM 64
#define NHEAD 32

typedef __attribute__((address_space(1))) const void gas;
typedef __attribute__((address_space(3))) void las;

// ---------------- pre-pass: K -> bf16 [h][s][d], V -> bf16 transposed [h][d][s] ----------------
__global__ __launch_bounds__(256) void convert_kv(const float* __restrict__ K,
                                                  const float* __restrict__ V,
                                                  __bf16* __restrict__ Kb,
                                                  __bf16* __restrict__ Vtg) {
    const int head = blockIdx.y;              // 32
    const int s0   = blockIdx.x * 64;         // 32 chunks of 64 keys
    const int tr   = threadIdx.x >> 2;        // 0..63
    const int tc   = (threadIdx.x & 3) << 4;  // 0,16,32,48
    const size_t ib = (size_t)head * (S_LEN * D_DIM) + (size_t)(s0 + tr) * D_DIM + tc;

    __shared__ __bf16 tb[64][72];

    {   // K: straight convert, coalesced in/out
        const float* kr = K + ib;
        f32x4 a = *(const f32x4*)kr, b = *(const f32x4*)(kr + 4),
              c = *(const f32x4*)(kr + 8), d = *(const f32x4*)(kr + 12);
        bf16x8 o0, o1;
        #pragma unroll
        for (int e = 0; e < 4; ++e) {
            o0[e] = (__bf16)a[e]; o0[e + 4] = (__bf16)b[e];
            o1[e] = (__bf16)c[e]; o1[e + 4] = (__bf16)d[e];
        }
        __bf16* ko = Kb + ib;
        *(bf16x8*)ko = o0; *(bf16x8*)(ko + 8) = o1;
    }
    {   // V: transpose 64x64 tile via LDS
        const float* vr = V + ib;
        f32x4 a = *(const f32x4*)vr, b = *(const f32x4*)(vr + 4),
              c = *(const f32x4*)(vr + 8), d = *(const f32x4*)(vr + 12);
        #pragma unroll
        for (int e = 0; e < 4; ++e) {
            tb[tc +  e][tr] = (__bf16)a[e];
            tb[tc + 4 + e][tr] = (__bf16)b[e];
            tb[tc + 8 + e][tr] = (__bf16)c[e];
            tb[tc + 12 + e][tr] = (__bf16)d[e];
        }
    }
    __syncthreads();
    {   // write Vt rows: d = tr, keys s0+tc..+15
        bf16x8 o0, o1;
        #pragma unroll
        for (int e = 0; e < 8; ++e) { o0[e] = tb[tr][tc + e]; o1[e] = tb[tr][tc + 8 + e]; }
        __bf16* vo = Vtg + (size_t)head * (D_DIM * S_LEN) + (size_t)tr * S_LEN + s0 + tc;
        *(bf16x8*)vo = o0; *(bf16x8*)(vo + 8) = o1;
    }
}

// ---------------- main: flash attention, DMA-staged bf16 K/V ----------------
__global__ __launch_bounds__(256, 4) void attn_fwd(const float* __restrict__ Q,
                                                   const __bf16* __restrict__ Kb,
                                                   const __bf16* __restrict__ Vg,
                                                   float* __restrict__ O) {
    // Deterministic CU-pairing + XCD-locality mapping (1024 blocks, 4/CU).
    const int b    = blockIdx.x;
    const int xcd  = b & 7;
    const int cs   = (b >> 3) & 31;
    const int j    = b >> 8;                  // 0..3
    const int head = xcd * 4 + (cs >> 3);     // 4 heads per XCD
    const int slot = cs & 7;
    const int chunk = (j == 0) ? slot : (j == 1) ? (31 - slot)
                    : (j == 2) ? (slot + 8) : (23 - slot);   // 64-row q-chunk, 0..31

    const int tid  = threadIdx.x;
    const int wave = tid >> 6;
    const int lane = tid & 63;
    const int l15  = lane & 15;
    const int lhi  = lane >> 4;

    const int q0 = chunk * 64 + wave * 16;    // wave owns rows q0..q0+15
    const size_t qbase = (size_t)head * (S_LEN * D_DIM);
    const size_t vbase = (size_t)head * (D_DIM * S_LEN);
    const float qscale = 0.125f * 1.44269504088896340736f;   // D^-0.5 * log2(e)

    __shared__ __align__(16) __bf16 Klds[2][64][64];   // [buf][key][d], 16B-unit col ^ (key&7)
    __shared__ __align__(16) __bf16 Vt[2][64][64];     // [buf][d][key], 16B-unit col ^ (d&7)
    __shared__ __align__(16) __bf16 Plds[4][16][64];   // per wave [q][key]

    // per-lane pre-swizzled gload_lds source offsets (row base always = 0 mod 8)
    const int xsw = (lane & 7) ^ ((lane >> 3) & 7);
    const size_t kOff = (size_t)(lane >> 3) * D_DIM + (size_t)xsw * 8;
    const size_t vOff = (size_t)(lane >> 3) * S_LEN + (size_t)xsw * 8;
    const __bf16* kgw = Kb + qbase + (size_t)(wave * 16) * D_DIM + kOff;
    const __bf16* vgw = Vg + vbase + (size_t)(wave * 16) * S_LEN + vOff;

    // ---- Q fragments (B-frag for swapped QK^T: col=l15, k=lhi*8+e) ----
    bf16x8 qf[2];
    {
        const float* qrow = Q + qbase + (size_t)(q0 + l15) * D_DIM + lhi * 8;
        #pragma unroll
        for (int h = 0; h < 2; ++h) {
            f32x4 a = *(const f32x4*)(qrow + h * 32);
            f32x4 bq = *(const f32x4*)(qrow + h * 32 + 4);
            bf16x8 t;
            #pragma unroll
            for (int e = 0; e < 4; ++e) { t[e] = (__bf16)(a[e] * qscale); t[e + 4] = (__bf16)(bq[e] * qscale); }
            qf[h] = t;
        }
    }

    f32x4 acc[4];
    #pragma unroll
    for (int td = 0; td < 4; ++td) acc[td] = (f32x4){0.f, 0.f, 0.f, 0.f};
    float m_r = -1e30f, l_r = 0.f;            // per-lane: q-row = q0 + l15

    // wave stages K rows [w*16,+16) and V d-rows [w*16,+16): 4 x gload_lds(16B)
    auto stage = [&](int kv0, int bufi) {
        const __bf16* kg = kgw + (size_t)kv0 * D_DIM;
        const __bf16* vg = vgw + kv0;
        __builtin_amdgcn_global_load_lds((gas*)kg,                 (las*)&Klds[bufi][wave * 16][0],     16, 0, 0);
        __builtin_amdgcn_global_load_lds((gas*)(kg + 8 * D_DIM),   (las*)&Klds[bufi][wave * 16 + 8][0], 16, 0, 0);
        __builtin_amdgcn_global_load_lds((gas*)vg,                 (las*)&Vt[bufi][wave * 16][0],       16, 0, 0);
        __builtin_amdgcn_global_load_lds((gas*)(vg + 8 * S_LEN),   (las*)&Vt[bufi][wave * 16 + 8][0],   16, 0, 0);
    };

    stage(0, 0);

    const int nt = chunk + 1;
    for (int kt = 0; kt < nt; ++kt) {
        const int cur = kt & 1;
        asm volatile("s_waitcnt vmcnt(0)" ::: "memory");
        __syncthreads();                 // buf[cur] fully staged by all waves

        if (kt + 1 < nt) stage((kt + 1) << 6, cur ^ 1);   // prefetch; drains at next barrier

        // ---- S^T = K Q^T : C/D col = q = l15, row = k = kv0 + ct*16 + lhi*4 + r ----
        f32x4 s[4];
        #pragma unroll
        for (int ct = 0; ct < 4; ++ct) s[ct] = (f32x4){0.f, 0.f, 0.f, 0.f};
        __builtin_amdgcn_s_setprio(1);
        #pragma unroll
        for (int h = 0; h < 2; ++h) {
            #pragma unroll
            for (int ct = 0; ct < 4; ++ct) {
                const int krow = ct * 16 + l15;
                bf16x8 kf = *(const bf16x8*)&Klds[cur][krow][(h * 32 + lhi * 8) ^ ((l15 & 7) << 3)];
                s[ct] = __builtin_amdgcn_mfma_f32_16x16x32_bf16(kf, qf[h], s[ct], 0, 0, 0);
            }
        }
        __builtin_amdgcn_s_setprio(0);

        // ---- causal mask: only the last tile straddles the diagonal ----
        if (kt == nt - 1) {
            const int kv0 = kt << 6;
            const int qg = q0 + l15;
            #pragma unroll
            for (int ct = 0; ct < 4; ++ct)
                #pragma unroll
                for (int r = 0; r < 4; ++r) {
                    const int kg = kv0 + ct * 16 + lhi * 4 + r;
                    if (kg > qg) s[ct][r] = -1e30f;
                }
        }

        // ---- in-register online softmax (lane owns one q-row's 16 scores) ----
        float mm = fmaxf(fmaxf(fmaxf(s[0][0], s[0][1]), fmaxf(s[0][2], s[0][3])),
                         fmaxf(fmaxf(s[1][0], s[1][1]), fmaxf(s[1][2], s[1][3])));
        mm = fmaxf(mm, fmaxf(fmaxf(fmaxf(s[2][0], s[2][1]), fmaxf(s[2][2], s[2][3])),
                             fmaxf(fmaxf(s[3][0], s[3][1]), fmaxf(s[3][2], s[3][3]))));
        mm = fmaxf(mm, __shfl_xor(mm, 16));
        mm = fmaxf(mm, __shfl_xor(mm, 32));
        if (!__all(mm - m_r <= 8.0f)) {          // defer-max (T13): rescale rarely
            const float mn = fmaxf(m_r, mm);
            const float f = exp2f(m_r - mn);
            m_r = mn;
            l_r *= f;
            #pragma unroll
            for (int r = 0; r < 4; ++r) {
                const float fr = __shfl(f, lhi * 4 + r);   // factor for acc row q=lhi*4+r
                #pragma unroll
                for (int td = 0; td < 4; ++td) acc[td][r] *= fr;
            }
        }
        float ps = 0.f;
        #pragma unroll
        for (int ct = 0; ct < 4; ++ct)
            #pragma unroll
            for (int r = 0; r < 4; ++r) {
                const float p = exp2f(s[ct][r] - m_r);
                s[ct][r] = p;
                ps += p;
            }
        ps += __shfl_xor(ps, 16);
        ps += __shfl_xor(ps, 32);
        l_r += ps;

        // ---- P (S^T layout) -> per-wave LDS (swizzled b64 writes) -> A-frags ----
        #pragma unroll
        for (int ct = 0; ct < 4; ++ct) {
            union { __bf16 h[4]; unsigned long long u; } pw;
            #pragma unroll
            for (int r = 0; r < 4; ++r) pw.h[r] = (__bf16)s[ct][r];
            *(unsigned long long*)&Plds[wave][l15][(ct * 16 + lhi * 4) ^ ((l15 & 7) << 3)] = pw.u;
        }
        asm volatile("s_waitcnt lgkmcnt(0)" ::: "memory");
        bf16x8 pf[2];
        #pragma unroll
        for (int kh = 0; kh < 2; ++kh)
            pf[kh] = *(const bf16x8*)&Plds[wave][l15][(kh * 32 + lhi * 8) ^ ((l15 & 7) << 3)];
        asm volatile("" ::: "memory");

        // ---- O += P V ----
        __builtin_amdgcn_s_setprio(1);
        #pragma unroll
        for (int kh = 0; kh < 2; ++kh) {
            #pragma unroll
            for (int td = 0; td < 4; ++td) {
                const int vrow = td * 16 + l15;
                bf16x8 vf = *(const bf16x8*)&Vt[cur][vrow][(kh * 32 + lhi * 8) ^ ((vrow & 7) << 3)];
                acc[td] = __builtin_amdgcn_mfma_f32_16x16x32_bf16(pf[kh], vf, acc[td], 0, 0, 0);
            }
        }
        __builtin_amdgcn_s_setprio(0);
    }

    // ---- epilogue: O = acc / l  (l for row q=lhi*4+r lives on lane lhi*4+r) ----
    float* orow = O + qbase + (size_t)q0 * D_DIM;
    #pragma unroll
    for (int r = 0; r < 4; ++r) {
        const float inv = 1.0f / __shfl(l_r, lhi * 4 + r);
        #pragma unroll
        for (int td = 0; td < 4; ++td)
            orow[(size_t)(lhi * 4 + r) * D_DIM + td * 16 + l15] = acc[td][r] * inv;
    }
}

// ---------------- fallback (round-5 kernel, fp32 inputs) if ws too small ----------------
__global__ __launch_bounds__(256, 4) void attn_fwd_fb(const float* __restrict__ Q,
                                                      const float* __restrict__ K,
                                                      const float* __restrict__ V,
                                                      float* __restrict__ O) {
    const int b    = blockIdx.x;
    const int xcd  = b & 7;
    const int cs   = (b >> 3) & 31;
    const int j    = b >> 8;
    const int head = xcd * 4 + (cs >> 3);
    const int slot = cs & 7;
    const int chunk = (j == 0) ? slot : (j == 1) ? (31 - slot)
                    : (j == 2) ? (slot + 8) : (23 - slot);

    const int tid  = threadIdx.x;
    const int wave = tid >> 6;
    const int lane = tid & 63;
    const int l15  = lane & 15;
    const int lhi  = lane >> 4;

    const int q0 = chunk * 64 + wave * 16;
    const size_t base = (size_t)head * (S_LEN * D_DIM);
    const float qscale = 0.125f * 1.44269504088896340736f;

    __shared__ __align__(16) __bf16 Klds[2][64][64];
    __shared__ __align__(16) __bf16 Vt[2][64][64];
    __shared__ __align__(16) __bf16 Plds[4][16][64];

    const int rk = tid >> 2;
    const int ck = (tid & 3) << 4;
    const int kp = tid & 31;
    const int dc = tid >> 5;
    const int swk = (rk & 7) << 3;

    bf16x8 qf[2];
    {
        const float* qrow = Q + base + (size_t)(q0 + l15) * D_DIM + lhi * 8;
        #pragma unroll
        for (int h = 0; h < 2; ++h) {
            f32x4 a = *(const f32x4*)(qrow + h * 32);
            f32x4 bq = *(const f32x4*)(qrow + h * 32 + 4);
            bf16x8 t;
            #pragma unroll
            for (int e = 0; e < 4; ++e) { t[e] = (__bf16)(a[e] * qscale); t[e + 4] = (__bf16)(bq[e] * qscale); }
            qf[h] = t;
        }
    }

    f32x4 acc[4];
    #pragma unroll
    for (int td = 0; td < 4; ++td) acc[td] = (f32x4){0.f, 0.f, 0.f, 0.f};
    float m_r = -1e30f, l_r = 0.f;

    f32x4 pk[4], pva[2], pvb[2];
    {
        const float* ks = K + base + (size_t)rk * D_DIM + ck;
        #pragma unroll
        for (int i = 0; i < 4; ++i) pk[i] = *(const f32x4*)(ks + 4 * i);
        const float* v0 = V + base + (size_t)(2 * kp) * D_DIM + dc * 8;
        pva[0] = *(const f32x4*)v0;           pva[1] = *(const f32x4*)(v0 + 4);
        pvb[0] = *(const f32x4*)(v0 + D_DIM); pvb[1] = *(const f32x4*)(v0 + D_DIM + 4);
        bf16x8 k0, k1;
        #pragma unroll
        for (int e = 0; e < 4; ++e) {
            k0[e] = (__bf16)pk[0][e]; k0[e + 4] = (__bf16)pk[1][e];
            k1[e] = (__bf16)pk[2][e]; k1[e + 4] = (__bf16)pk[3][e];
        }
        *(bf16x8*)&Klds[0][rk][ck ^ swk] = k0;
        *(bf16x8*)&Klds[0][rk][(ck + 8) ^ swk] = k1;
        #pragma unroll
        for (int jj = 0; jj < 8; ++jj) {
            const int d = dc * 8 + jj;
            const float av = (jj < 4) ? pva[0][jj & 3] : pva[1][jj & 3];
            const float bv = (jj < 4) ? pvb[0][jj & 3] : pvb[1][jj & 3];
            union { __bf16 h[2]; unsigned int u; } t;
            t.h[0] = (__bf16)av; t.h[1] = (__bf16)bv;
            *(unsigned int*)&Vt[0][d][(2 * kp) ^ ((d & 7) << 3)] = t.u;
        }
    }

    const int nt = chunk + 1;
    for (int kt = 0; kt < nt; ++kt) {
        const int cur = kt & 1;
        __syncthreads();
        const bool pre = (kt + 1 < nt);
        if (pre) {
            const int kv1 = (kt + 1) << 6;
            const float* ks = K + base + (size_t)(kv1 + rk) * D_DIM + ck;
            #pragma unroll
            for (int i = 0; i < 4; ++i) pk[i] = *(const f32x4*)(ks + 4 * i);
            const float* v0 = V + base + (size_t)(kv1 + 2 * kp) * D_DIM + dc * 8;
            pva[0] = *(const f32x4*)v0;           pva[1] = *(const f32x4*)(v0 + 4);
            pvb[0] = *(const f32x4*)(v0 + D_DIM); pvb[1] = *(const f32x4*)(v0 + D_DIM + 4);
        }

        f32x4 s[4];
        #pragma unroll
        for (int ct = 0; ct < 4; ++ct) s[ct] = (f32x4){0.f, 0.f, 0.f, 0.f};
        #pragma unroll
        for (int h = 0; h < 2; ++h) {
            #pragma unroll
            for (int ct = 0; ct < 4; ++ct) {
                const int krow = ct * 16 + l15;
                bf16x8 kf = *(const bf16x8*)&Klds[cur][krow][(h * 32 + lhi * 8) ^ ((l15 & 7) << 3)];
                s[ct] = __builtin_amdgcn_mfma_f32_16x16x32_bf16(kf, qf[h], s[ct], 0, 0, 0);
            }
        }

        if (kt == nt - 1) {
            const int kv0 = kt << 6;
            const int qg = q0 + l15;
            #pragma unroll
            for (int ct = 0; ct < 4; ++ct)
                #pragma unroll
                for (int r = 0; r < 4; ++r) {
                    const int kg = kv0 + ct * 16 + lhi * 4 + r;
                    if (kg > qg) s[ct][r] = -1e30f;
                }
        }

        float mm = fmaxf(fmaxf(fmaxf(s[0][0], s[0][1]), fmaxf(s[0][2], s[0][3])),
                         fmaxf(fmaxf(s[1][0], s[1][1]), fmaxf(s[1][2], s[1][3])));
        mm = fmaxf(mm, fmaxf(fmaxf(fmaxf(s[2][0], s[2][1]), fmaxf(s[2][2], s[2][3])),
                             fmaxf(fmaxf(s[3][0], s[3][1]), fmaxf(s[3][2], s[3][3]))));
        mm = fmaxf(mm, __shfl_xor(mm, 16));
        mm = fmaxf(mm, __shfl_xor(mm, 32));
        if (!__all(mm - m_r <= 8.0f)) {
            const float mn = fmaxf(m_r, mm);
            const float f = exp2f(m_r - mn);
            m_r = mn;
            l_r *= f;
            #pragma unroll
            for (int r = 0; r < 4; ++r) {
                const float fr = __shfl(f, lhi * 4 + r);
                #pragma unroll
                for (int td = 0; td < 4; ++td) acc[td][r] *= fr;
            }
        }
        float ps = 0.f;
        #pragma unroll
        for (int ct = 0; ct < 4; ++ct)
            #pragma unroll
            for (int r = 0; r < 4; ++r) {
                const float p = exp2f(s[ct][r] - m_r);
                s[ct][r] = p;
                ps += p;
            }
        ps += __shfl_xor(ps, 16);
        ps += __shfl_xor(ps, 32);
        l_r += ps;

        #pragma unroll
        for (int ct = 0; ct < 4; ++ct) {
            union { __bf16 h[4]; unsigned long long u; } pw;
            #pragma unroll
            for (int r = 0; r < 4; ++r) pw.h[r] = (__bf16)s[ct][r];
            *(unsigned long long*)&Plds[wave][l15][(ct * 16 + lhi * 4) ^ ((l15 & 7) << 3)] = pw.u;
        }
        asm volatile("s_waitcnt lgkmcnt(0)" ::: "memory");
        bf16x8 pf[2];
        #pragma unroll
        for (int kh = 0; kh < 2; ++kh)
            pf[kh] = *(const bf16x8*)&Plds[wave][l15][(kh * 32 + lhi * 8) ^ ((l15 & 7) << 3)];
        asm volatile("" ::: "memory");

        #pragma unroll
        for (int kh = 0; kh < 2; ++kh) {
            #pragma unroll
            for (int td = 0; td < 4; ++td) {
                const int vrow = td * 16 + l15;
                bf16x8 vf = *(const bf16x8*)&Vt[cur][vrow][(kh * 32 + lhi * 8) ^ ((vrow & 7) << 3)];
                acc[td] = __builtin_amdgcn_mfma_f32_16x16x32_bf16(pf[kh], vf, acc[td], 0, 0, 0);
            }
        }

        if (pre) {
            const int nxt = cur ^ 1;
            bf16x8 k0, k1;
            #pragma unroll
            for (int e = 0; e < 4; ++e) {
                k0[e] = (__bf16)pk[0][e]; k0[e + 4] = (__bf16)pk[1][e];
                k1[e] = (__bf16)pk[2][e]; k1[e + 4] = (__bf16)pk[3][e];
            }
            *(bf16x8*)&Klds[nxt][rk][ck ^ swk] = k0;
            *(bf16x8*)&Klds[nxt][rk][(ck + 8) ^ swk] = k1;
            #pragma unroll
            for (int jj = 0; jj < 8; ++jj) {
                const int d = dc * 8 + jj;
                const float av = (jj < 4) ? pva[0][jj & 3] : pva[1][jj & 3];
                const float bv = (jj < 4) ? pvb[0][jj & 3] : pvb[1][jj & 3];
                union { __bf16 h[2]; unsigned int u; } t;
                t.h[0] = (__bf16)av; t.h[1] = (__bf16)bv;
                *(unsigned int*)&Vt[nxt][d][(2 * kp) ^ ((d & 7) << 3)] = t.u;
            }
        }
    }

    float* orow = O + base + (size_t)q0 * D_DIM;
    #pragma unroll
    for (int r = 0; r < 4; ++r) {
        const float inv = 1.0f / __shfl(l_r, lhi * 4 + r);
        #pragma unroll
        for (int td = 0; td < 4; ++td)
            orow[(size_t)(lhi * 4 + r) * D_DIM + td * 16 + l15] = acc[td][r] * inv;
    }
}

extern "C" void kernel_launch(void* const* d_in, const int* in_sizes, int n_in,
                              void* d_out, int out_size, void* d_ws, size_t ws_size,
                              hipStream_t stream) {
    const float* q = (const float*)d_in[0];
    const float* k = (const float*)d_in[1];
    const float* v = (const float*)d_in[2];
    float* o = (float*)d_out;
    const size_t elems = (size_t)NHEAD * S_LEN * D_DIM;
    if (ws_size >= 2 * elems * sizeof(__bf16)) {
        __bf16* Kb  = (__bf16*)d_ws;
        __bf16* Vtg = Kb + elems;
        convert_kv<<<dim3(32, 32), dim3(256), 0, stream>>>(k, v, Kb, Vtg);
        attn_fwd<<<dim3(1024), dim3(256), 0, stream>>>(q, Kb, Vtg, o);
    } else {
        attn_fwd_fb<<<dim3(1024), dim3(256), 0, stream>>>(q, k, v, o);
    }
}